// Round 16
// baseline (373.649 us; speedup 1.0000x reference)
//
#include <hip/hip_runtime.h>

typedef unsigned short u16;
typedef unsigned int u32;
typedef short short8 __attribute__((ext_vector_type(8)));
typedef float f32x4 __attribute__((ext_vector_type(4)));

#define T_LEN 512
#define NCLS 19

#define L2E 1.4426950408889634f
#define TL2E 2.8853901617765067f

static __device__ __forceinline__ u16 f2bf(float f) {
  u32 u = __float_as_uint(f);
  u32 r = (u + 0x7FFFu + ((u >> 16) & 1u)) >> 16;
  return (u16)r;
}
static __device__ __forceinline__ float bf2f(u16 h) {
  return __uint_as_float(((u32)h) << 16);
}
static __device__ __forceinline__ float rcp_f(float x) { return __builtin_amdgcn_rcpf(x); }
static __device__ __forceinline__ float ex2(float x) { return __builtin_amdgcn_exp2f(x); }

// ---------------- fused embed + weight prep (one launch) ---------------------------
// blocks 0..8191: embedding gather -> xs[t*B+b][d] bf16
// blocks 8192..9215: wt_bf[dir][p][k] gate-interleaved, log2e-prescaled
// block 9216: bias_pre
__global__ __launch_bounds__(256) void k_embed_prep(const int* __restrict__ ids,
                                                    const float* __restrict__ table,
                                                    const float* __restrict__ fw_k,
                                                    const float* __restrict__ bw_k,
                                                    const float* __restrict__ fw_b,
                                                    const float* __restrict__ bw_b,
                                                    u16* __restrict__ xs,
                                                    u16* __restrict__ wt_bf,
                                                    float* __restrict__ bias_pre) {
  int wg = blockIdx.x;
  int tid = threadIdx.x;
  if (wg < 8192) {
    int i = wg * 256 + tid;
    int e = i * 4;               // element index, total T*B*D = 8388608
    int m = e >> 7;              // row = t*B + b
    int col = e & 127;
    int t = m >> 7, b = m & 127;
    int id = ids[b * T_LEN + t];
    float4 v = *(const float4*)(table + (size_t)id * 128 + col);
    ushort4 o;
    o.x = f2bf(v.x); o.y = f2bf(v.y); o.z = f2bf(v.z); o.w = f2bf(v.w);
    *(ushort4*)(xs + (size_t)m * 128 + col) = o;
  } else if (wg < 9216) {
    int i = (wg - 8192) * 256 + tid;
    int n = i >> 8, k = i & 255;
    int dir = n >> 9, p = n & 511;
    int w = p >> 6, nt = (p >> 4) & 3, g4 = (p >> 2) & 3, q = p & 3;
    int u = w * 16 + g4 * 4 + nt;
    int j = q * 128 + u;
    float sc = (q == 1) ? TL2E : L2E;
    const float* K = dir ? bw_k : fw_k;
    wt_bf[i] = f2bf(K[k * 512 + j] * sc);
  } else {
    for (int uu = 0; uu < 4; uu++) {
      int n = uu * 256 + tid;
      int dir = n >> 9, p = n & 511;
      int w = p >> 6, nt = (p >> 4) & 3, g4 = (p >> 2) & 3, q = p & 3;
      int u = w * 16 + g4 * 4 + nt;
      int j = q * 128 + u;
      float sc = (q == 1) ? TL2E : L2E;
      float bv = (dir ? bw_b : fw_b)[j] + (q == 2 ? 1.0f : 0.0f);
      bias_pre[n] = bv * sc;
    }
  }
}

// ---------------- fused LSTM: 64 WGs, in-accumulator activation, dbuf xstage -------
// r15 frame. Deltas: (1) xstage double-buffered [2][16][524]; the x-block runs
// BEFORE the step barrier, writing the OTHER buffer while activation reads the
// current one (disjoint -> race-free) — exactly ONE barrier per step; its MFMAs
// overlap the activation's trans latency. (2) t-loop unrolled x4: CUR/NXT, xstage
// row, and x-block trigger are compile-time.
__global__ __launch_bounds__(512, 2) void k_lstm(const u16* __restrict__ wt_bf,
                                                 const float* __restrict__ bias_pre,
                                                 const u16* __restrict__ xs,
                                                 u16* __restrict__ hs_fw,
                                                 u16* __restrict__ hs_bw) {
  __shared__ u16 hbuf[2][4][144];       // double-buffered h, 288B rows (padded)
  __shared__ float xstage[2][16][524];  // z_x dbuf: [blockbuf][so*4+cbv][gate p]
  int tid = threadIdx.x;
  int wg = blockIdx.x;
  int dir = wg >> 5;
  int bb = (wg & 31) * 4;             // batch base (4 per WG)
  int w = tid >> 6, l = tid & 63;
  int cb = l & 15, g4 = l >> 4;
  int cbv = cb & 3;                   // batch index within group
  int so = cb >> 2;                   // this lane's tile/step-offset role

  // resident A-frags: W^T full K=256 (128 regs -> AGPRs), r9/r11-verbatim indices
  short8 wf[32];
#pragma unroll
  for (int n = 0; n < 4; n++) {
    const u16* wb = wt_bf + ((size_t)(dir * 512 + w * 64 + n * 16 + cb) * 256) + g4 * 8;
#pragma unroll
    for (int ks = 0; ks < 8; ks++)
      wf[n * 8 + ks] = *(const short8*)(wb + ks * 32);
  }
  f32x4 bias4[4];
#pragma unroll
  for (int n = 0; n < 4; n++)
    bias4[n] = *(const f32x4*)(bias_pre + dir * 512 + w * 64 + n * 16 + g4 * 4);

  float c = 0.0f;                     // cell state for (batch cbv, unit u_so)
  int u_so = w * 16 + g4 * 4 + so;

  int roff[4];
#pragma unroll
  for (int ks = 0; ks < 4; ks++)
    roff[ks] = cbv * 288 + ks * 64 + g4 * 16;   // bytes into a hbuf slot (row=288B)
  int xcol = w * 256 + g4 * 16;                 // byte offset within an xstage row: + n*64

  // zero both h buffers (h(0)=0): 2*4*144 u16 = 576 u32
  u32* hz = (u32*)hbuf;
  hz[tid >= 512 ? 0 : tid] = 0;
  if (tid < 64) hz[512 + tid] = 0;
  __syncthreads();

  int t0a = dir ? (T_LEN - 1) : 0;
  int stp = dir ? -1 : 1;
  u16* hsout = dir ? hs_bw : hs_fw;
  long step1 = (long)stp * 16384;     // one time step, elements

  const u16* xb0 = xs + ((size_t)(t0a * 128 + bb + cbv) * 128) + g4 * 8;  // step 0 base
  u16* ph = hsout + ((size_t)(t0a * 128 + bb + cbv) * 128) + u_so;

  // ---- prologue: x-block (z_x incl. bias) for steps 0..3 into buf 0 ----
  short8 xblk[4];
  {
    const u16* p = xb0 + (long)so * step1;
#pragma unroll
    for (int ks = 0; ks < 4; ks++) xblk[ks] = *(const short8*)(p + ks * 32);
  }
#pragma unroll
  for (int n = 0; n < 4; n++) {
    f32x4 xacc = bias4[n];
    xacc = __builtin_amdgcn_mfma_f32_16x16x32_bf16(wf[n * 8 + 0], xblk[0], xacc, 0, 0, 0);
    xacc = __builtin_amdgcn_mfma_f32_16x16x32_bf16(wf[n * 8 + 1], xblk[1], xacc, 0, 0, 0);
    xacc = __builtin_amdgcn_mfma_f32_16x16x32_bf16(wf[n * 8 + 2], xblk[2], xacc, 0, 0, 0);
    xacc = __builtin_amdgcn_mfma_f32_16x16x32_bf16(wf[n * 8 + 3], xblk[3], xacc, 0, 0, 0);
    *(f32x4*)((char*)&xstage[0][cb][0] + xcol + n * 64) = xacc;
  }
  {
    const u16* p = xb0 + (long)(4 + so) * step1;   // preload x for block of steps 4..7
#pragma unroll
    for (int ks = 0; ks < 4; ks++) xblk[ks] = *(const short8*)(p + ks * 32);
  }
  asm volatile("s_waitcnt lgkmcnt(0)" ::: "memory");
  __builtin_amdgcn_s_barrier();
  asm volatile("" ::: "memory");

  for (int tt = 0; tt < 128; tt++) {
    int bs = tt & 1;
#pragma unroll
    for (int j = 0; j < 4; j++) {
      // ---- h-MFMAs (acc init 0), all in registers; hbuf[j&1] is current ----
      const char* hrow = (const char*)&hbuf[j & 1][0][0];
      short8 hf0 = *(const short8*)(hrow + roff[0]);
      short8 hf1 = *(const short8*)(hrow + roff[1]);
      short8 hf2 = *(const short8*)(hrow + roff[2]);
      short8 hf3 = *(const short8*)(hrow + roff[3]);
      f32x4 a0 = {0.f, 0.f, 0.f, 0.f}, a1 = a0, a2 = a0, a3 = a0;
      a0 = __builtin_amdgcn_mfma_f32_16x16x32_bf16(wf[4],  hf0, a0, 0, 0, 0);
      a1 = __builtin_amdgcn_mfma_f32_16x16x32_bf16(wf[12], hf0, a1, 0, 0, 0);
      a2 = __builtin_amdgcn_mfma_f32_16x16x32_bf16(wf[20], hf0, a2, 0, 0, 0);
      a3 = __builtin_amdgcn_mfma_f32_16x16x32_bf16(wf[28], hf0, a3, 0, 0, 0);
      a0 = __builtin_amdgcn_mfma_f32_16x16x32_bf16(wf[5],  hf1, a0, 0, 0, 0);
      a1 = __builtin_amdgcn_mfma_f32_16x16x32_bf16(wf[13], hf1, a1, 0, 0, 0);
      a2 = __builtin_amdgcn_mfma_f32_16x16x32_bf16(wf[21], hf1, a2, 0, 0, 0);
      a3 = __builtin_amdgcn_mfma_f32_16x16x32_bf16(wf[29], hf1, a3, 0, 0, 0);
      a0 = __builtin_amdgcn_mfma_f32_16x16x32_bf16(wf[6],  hf2, a0, 0, 0, 0);
      a1 = __builtin_amdgcn_mfma_f32_16x16x32_bf16(wf[14], hf2, a1, 0, 0, 0);
      a2 = __builtin_amdgcn_mfma_f32_16x16x32_bf16(wf[22], hf2, a2, 0, 0, 0);
      a3 = __builtin_amdgcn_mfma_f32_16x16x32_bf16(wf[30], hf2, a3, 0, 0, 0);
      a0 = __builtin_amdgcn_mfma_f32_16x16x32_bf16(wf[7],  hf3, a0, 0, 0, 0);
      a1 = __builtin_amdgcn_mfma_f32_16x16x32_bf16(wf[15], hf3, a1, 0, 0, 0);
      a2 = __builtin_amdgcn_mfma_f32_16x16x32_bf16(wf[23], hf3, a2, 0, 0, 0);
      a3 = __builtin_amdgcn_mfma_f32_16x16x32_bf16(wf[31], hf3, a3, 0, 0, 0);
      // ---- select own tile (lane-varying cndmask, no runtime indexing) ----
      f32x4 zA = (so & 2) ? a2 : a0;
      f32x4 zB = (so & 2) ? a3 : a1;
      f32x4 zh = (so & 1) ? zB : zA;
      f32x4 zx = *(const f32x4*)&xstage[bs][j * 4 + cbv][w * 64 + so * 16 + g4 * 4];
      float z0 = zh[0] + zx[0];
      float z1 = zh[1] + zx[1];
      float z2 = zh[2] + zx[2];
      float z3 = zh[3] + zx[3];
      float A2 = ex2(-z0);                   // e^-zi
      float B2 = ex2(z1);                    // e^{2zj}
      float F2 = ex2(-z2);                   // e^-(zf+1)
      float O2 = ex2(-z3);                   // e^-zo
      float r1 = rcp_f((1.f + A2) * (1.f + B2));
      float rf = rcp_f(1.f + F2);
      float cn = fmaf(c, rf, (B2 - 1.f) * r1);
      c = cn;
      float C2 = ex2(cn * TL2E);             // e^{2c}
      float r2 = rcp_f((1.f + C2) * (1.f + O2));
      float hv = (C2 - 1.f) * r2;            // tanh(c)*sig(zo)
      u16 hb16 = f2bf(hv);
      hbuf[(j & 1) ^ 1][cbv][u_so] = hb16;   // all 64 lanes, bijective coverage
      *ph = hb16;
      ph += step1;
      if (j == 3 && tt < 127) {
        // x-block for steps 4*tt+4..+7 into the OTHER xstage buffer (no race with
        // this step's zx reads of buffer bs); overlaps the activation latency above.
#pragma unroll
        for (int n = 0; n < 4; n++) {
          f32x4 xacc = bias4[n];
          xacc = __builtin_amdgcn_mfma_f32_16x16x32_bf16(wf[n * 8 + 0], xblk[0], xacc, 0, 0, 0);
          xacc = __builtin_amdgcn_mfma_f32_16x16x32_bf16(wf[n * 8 + 1], xblk[1], xacc, 0, 0, 0);
          xacc = __builtin_amdgcn_mfma_f32_16x16x32_bf16(wf[n * 8 + 2], xblk[2], xacc, 0, 0, 0);
          xacc = __builtin_amdgcn_mfma_f32_16x16x32_bf16(wf[n * 8 + 3], xblk[3], xacc, 0, 0, 0);
          *(f32x4*)((char*)&xstage[bs ^ 1][cb][0] + xcol + n * 64) = xacc;
        }
        int ts = 4 * tt + 8 + so;            // next block's step for this lane
        if (ts > 511) ts = 511;              // clamp: in-bounds, value unused
        const u16* p = xb0 + (long)ts * step1;
#pragma unroll
        for (int ks = 0; ks < 4; ks++) xblk[ks] = *(const short8*)(p + ks * 32);
      }
      asm volatile("s_waitcnt lgkmcnt(0)" ::: "memory");
      __builtin_amdgcn_s_barrier();
      asm volatile("" ::: "memory");
    }
  }
}

// ---------------- attention + FC + argmax (+ fused l2 at block 128) ----------------
__global__ __launch_bounds__(512) void k_attn(const u16* __restrict__ hsf,
                                              const u16* __restrict__ hsb,
                                              const float* __restrict__ att_w,
                                              const float* __restrict__ fc_w,
                                              const float* __restrict__ fc_b,
                                              float* __restrict__ out) {
  __shared__ float rsum[8][128];
  __shared__ float esums[8];
  __shared__ float hstar[128];
  __shared__ float lg[NCLS];
  int tid = threadIdx.x, b = blockIdx.x;
  int w = tid >> 6, l = tid & 63;
  if (b == 128) {                       // fused l2 loss
    float a = 0.f;
    for (int i = tid; i < 128 * NCLS; i += 512) a += fc_w[i] * fc_w[i];
    if (tid < NCLS) a += fc_b[tid] * fc_b[tid];
#pragma unroll
    for (int o2 = 32; o2 >= 1; o2 >>= 1) a += __shfl_xor(a, o2, 64);
    if (l == 0) esums[w] = a;
    __syncthreads();
    if (tid == 0) {
      float s = 0.f;
#pragma unroll
      for (int i = 0; i < 8; i++) s += esums[i];
      out[2560] = 0.5f * s;
    }
    return;
  }
  float2 aw = *(const float2*)(att_w + 2 * l);
  float r0 = 0.f, r1 = 0.f, es = 0.f;
  for (int t = w; t < T_LEN; t += 8) {
    size_t o = ((size_t)t * 128 + b) * 128 + 2 * l;
    u32 vf = *(const u32*)(hsf + o);
    u32 vb = *(const u32*)(hsb + o);
    float h0 = bf2f((u16)vf) + bf2f((u16)vb);
    float h1 = bf2f((u16)(vf >> 16)) + bf2f((u16)(vb >> 16));
    float e0 = ex2(h0 * TL2E);
    float th0 = (e0 - 1.f) * rcp_f(e0 + 1.f);
    float e1 = ex2(h1 * TL2E);
    float th1 = (e1 - 1.f) * rcp_f(e1 + 1.f);
    float s = fmaf(th0, aw.x, th1 * aw.y);
#pragma unroll
    for (int o2 = 32; o2 >= 1; o2 >>= 1) s += __shfl_xor(s, o2, 64);
    float e = ex2(s * L2E);      // no max-subtraction: |s| bounded, e^s safe in f32
    r0 = fmaf(e, h0, r0); r1 = fmaf(e, h1, r1); es += e;
  }
  rsum[w][2 * l] = r0;
  rsum[w][2 * l + 1] = r1;
  if (l == 0) esums[w] = es;
  __syncthreads();
  if (tid < 128) {
    float r = 0.f, et = 0.f;
#pragma unroll
    for (int i = 0; i < 8; i++) { r += rsum[i][tid]; et += esums[i]; }
    float rr = r / et;
    float e2 = ex2(rr * TL2E);
    hstar[tid] = (e2 - 1.f) * rcp_f(e2 + 1.f);
  }
  __syncthreads();
  if (tid < NCLS) {
    float acc = fc_b[tid];
#pragma unroll 4
    for (int hh = 0; hh < 128; hh++) acc = fmaf(hstar[hh], fc_w[hh * NCLS + tid], acc);
    out[b * NCLS + tid] = acc;
    lg[tid] = acc;
  }
  __syncthreads();
  if (tid == 0) {
    int best = 0; float bv = lg[0];
    for (int l2 = 1; l2 < NCLS; l2++)
      if (lg[l2] > bv) { bv = lg[l2]; best = l2; }
    out[2432 + b] = (float)best;   // predict_label_ids
    out[2561 + b] = (float)best;   // probabilities (argmax of softmax == argmax)
  }
}

extern "C" void kernel_launch(void* const* d_in, const int* in_sizes, int n_in,
                              void* d_out, int out_size, void* d_ws, size_t ws_size,
                              hipStream_t stream) {
  const int* ids = (const int*)d_in[0];
  const float* table = (const float*)d_in[1];
  const float* fw_k = (const float*)d_in[2];
  const float* fw_b = (const float*)d_in[3];
  const float* bw_k = (const float*)d_in[4];
  const float* bw_b = (const float*)d_in[5];
  const float* att_w = (const float*)d_in[6];
  const float* fc_w = (const float*)d_in[7];
  const float* fc_b = (const float*)d_in[8];
  float* out = (float*)d_out;
  char* ws = (char*)d_ws;

  u16* xs = (u16*)(ws + 0);                    // 16,777,216 B   xs[t*128+b][128] bf16
  u16* wt_bf = (u16*)(ws + 16777216);          //    524,288 B   [2][512][256] bf16
  float* bias_pre = (float*)(ws + 17301504);   //      4,096 B
  u16* hs_fw = (u16*)(ws + 17305600);          // 16,777,216 B   [t][b][u] bf16
  u16* hs_bw = (u16*)(ws + 34082816);          // 16,777,216 B   (end 50,860,032)

  hipLaunchKernelGGL(k_embed_prep, dim3(9217), dim3(256), 0, stream, ids, table,
                     fw_k, bw_k, fw_b, bw_b, xs, wt_bf, bias_pre);
  hipLaunchKernelGGL(k_lstm, dim3(64), dim3(512), 0, stream, wt_bf, bias_pre, xs,
                     hs_fw, hs_bw);
  hipLaunchKernelGGL(k_attn, dim3(129), dim3(512), 0, stream, hs_fw, hs_bw, att_w,
                     fc_w, fc_b, out);
}

// Round 17
// 352.134 us; speedup vs baseline: 1.0611x; 1.0611x over previous
//
#include <hip/hip_runtime.h>

typedef unsigned short u16;
typedef unsigned int u32;
typedef short short8 __attribute__((ext_vector_type(8)));
typedef float f32x4 __attribute__((ext_vector_type(4)));

#define T_LEN 512
#define NCLS 19

#define L2E 1.4426950408889634f
#define TL2E 2.8853901617765067f

static __device__ __forceinline__ u16 f2bf(float f) {
  u32 u = __float_as_uint(f);
  u32 r = (u + 0x7FFFu + ((u >> 16) & 1u)) >> 16;
  return (u16)r;
}
static __device__ __forceinline__ float bf2f(u16 h) {
  return __uint_as_float(((u32)h) << 16);
}
static __device__ __forceinline__ float rcp_f(float x) { return __builtin_amdgcn_rcpf(x); }
static __device__ __forceinline__ float ex2(float x) { return __builtin_amdgcn_exp2f(x); }

// ---------------- fused embed + weight prep (one launch, r16-proven) ---------------
__global__ __launch_bounds__(256) void k_embed_prep(const int* __restrict__ ids,
                                                    const float* __restrict__ table,
                                                    const float* __restrict__ fw_k,
                                                    const float* __restrict__ bw_k,
                                                    const float* __restrict__ fw_b,
                                                    const float* __restrict__ bw_b,
                                                    u16* __restrict__ xs,
                                                    u16* __restrict__ wt_bf,
                                                    float* __restrict__ bias_pre) {
  int wg = blockIdx.x;
  int tid = threadIdx.x;
  if (wg < 8192) {
    int i = wg * 256 + tid;
    int e = i * 4;               // element index, total T*B*D = 8388608
    int m = e >> 7;              // row = t*B + b
    int col = e & 127;
    int t = m >> 7, b = m & 127;
    int id = ids[b * T_LEN + t];
    float4 v = *(const float4*)(table + (size_t)id * 128 + col);
    ushort4 o;
    o.x = f2bf(v.x); o.y = f2bf(v.y); o.z = f2bf(v.z); o.w = f2bf(v.w);
    *(ushort4*)(xs + (size_t)m * 128 + col) = o;
  } else if (wg < 9216) {
    int i = (wg - 8192) * 256 + tid;
    int n = i >> 8, k = i & 255;
    int dir = n >> 9, p = n & 511;
    int w = p >> 6, nt = (p >> 4) & 3, g4 = (p >> 2) & 3, q = p & 3;
    int u = w * 16 + g4 * 4 + nt;
    int j = q * 128 + u;
    float sc = (q == 1) ? TL2E : L2E;
    const float* K = dir ? bw_k : fw_k;
    wt_bf[i] = f2bf(K[k * 512 + j] * sc);
  } else {
    for (int uu = 0; uu < 4; uu++) {
      int n = uu * 256 + tid;
      int dir = n >> 9, p = n & 511;
      int w = p >> 6, nt = (p >> 4) & 3, g4 = (p >> 2) & 3, q = p & 3;
      int u = w * 16 + g4 * 4 + nt;
      int j = q * 128 + u;
      float sc = (q == 1) ? TL2E : L2E;
      float bv = (dir ? bw_b : fw_b)[j] + (q == 2 ? 1.0f : 0.0f);
      bias_pre[n] = bv * sc;
    }
  }
}

// ---------------- fused LSTM: r15-passing kernel, byte-for-byte --------------------
// 64 WGs, in-accumulator activation (cndmask tile select), single xstage buffer,
// one barrier/step (two on x-block steps, x-block AFTER B1 — overlaps other waves).
__global__ __launch_bounds__(512, 2) void k_lstm(const u16* __restrict__ wt_bf,
                                                 const float* __restrict__ bias_pre,
                                                 const u16* __restrict__ xs,
                                                 u16* __restrict__ hs_fw,
                                                 u16* __restrict__ hs_bw) {
  __shared__ u16 hbuf[2][4][144];     // double-buffered h, 288B rows (padded, r11)
  __shared__ float xstage[16][524];   // z_x for 4 steps: row = so*4+cbv, col = gate p
  int tid = threadIdx.x;
  int wg = blockIdx.x;
  int dir = wg >> 5;
  int bb = (wg & 31) * 4;             // batch base (4 per WG)
  int w = tid >> 6, l = tid & 63;
  int cb = l & 15, g4 = l >> 4;
  int cbv = cb & 3;                   // batch index within group
  int so = cb >> 2;                   // this lane's tile/step-offset role

  // resident A-frags: W^T full K=256 (128 regs -> AGPRs), r9/r11-verbatim indices
  short8 wf[32];
#pragma unroll
  for (int n = 0; n < 4; n++) {
    const u16* wb = wt_bf + ((size_t)(dir * 512 + w * 64 + n * 16 + cb) * 256) + g4 * 8;
#pragma unroll
    for (int ks = 0; ks < 8; ks++)
      wf[n * 8 + ks] = *(const short8*)(wb + ks * 32);
  }
  f32x4 bias4[4];
#pragma unroll
  for (int n = 0; n < 4; n++)
    bias4[n] = *(const f32x4*)(bias_pre + dir * 512 + w * 64 + n * 16 + g4 * 4);

  float c = 0.0f;                     // cell state for (batch cbv, unit u_so)
  int u_so = w * 16 + g4 * 4 + so;

  int roff[4];
#pragma unroll
  for (int ks = 0; ks < 4; ks++)
    roff[ks] = cbv * 288 + ks * 64 + g4 * 16;   // bytes into a hbuf slot (row=288B)
  int xcol = w * 256 + g4 * 16;                 // byte offset within an xstage row: + n*64

  // zero both h buffers (h(0)=0): 2*4*144 u16 = 576 u32
  u32* hz = (u32*)hbuf;
  hz[tid >= 512 ? 0 : tid] = 0;
  if (tid < 64) hz[512 + tid] = 0;
  __syncthreads();

  int t0a = dir ? (T_LEN - 1) : 0;
  int stp = dir ? -1 : 1;
  u16* hsout = dir ? hs_bw : hs_fw;
  long step1 = (long)stp * 16384;     // one time step, elements

  const u16* xb0 = xs + ((size_t)(t0a * 128 + bb + cbv) * 128) + g4 * 8;  // step 0 base
  u16* ph = hsout + ((size_t)(t0a * 128 + bb + cbv) * 128) + u_so;

  // ---- prologue: x-block (z_x incl. bias) for steps 0..3 ----
  short8 xblk[4];
  {
    const u16* p = xb0 + (long)so * step1;
#pragma unroll
    for (int ks = 0; ks < 4; ks++) xblk[ks] = *(const short8*)(p + ks * 32);
  }
#pragma unroll
  for (int n = 0; n < 4; n++) {
    f32x4 xacc = bias4[n];
    xacc = __builtin_amdgcn_mfma_f32_16x16x32_bf16(wf[n * 8 + 0], xblk[0], xacc, 0, 0, 0);
    xacc = __builtin_amdgcn_mfma_f32_16x16x32_bf16(wf[n * 8 + 1], xblk[1], xacc, 0, 0, 0);
    xacc = __builtin_amdgcn_mfma_f32_16x16x32_bf16(wf[n * 8 + 2], xblk[2], xacc, 0, 0, 0);
    xacc = __builtin_amdgcn_mfma_f32_16x16x32_bf16(wf[n * 8 + 3], xblk[3], xacc, 0, 0, 0);
    *(f32x4*)((char*)&xstage[cb][0] + xcol + n * 64) = xacc;
  }
  {
    const u16* p = xb0 + (long)(4 + so) * step1;   // reload for block of steps 4..7
#pragma unroll
    for (int ks = 0; ks < 4; ks++) xblk[ks] = *(const short8*)(p + ks * 32);
  }
  asm volatile("s_waitcnt lgkmcnt(0)" ::: "memory");
  __builtin_amdgcn_s_barrier();
  asm volatile("" ::: "memory");

  for (int t = 0; t < T_LEN; t++) {
    int CUR = t & 1, NXT = CUR ^ 1;
    // ---- h-MFMAs (acc init 0), all in registers ----
    const char* hrow = (const char*)&hbuf[CUR][0][0];
    short8 hf0 = *(const short8*)(hrow + roff[0]);
    short8 hf1 = *(const short8*)(hrow + roff[1]);
    short8 hf2 = *(const short8*)(hrow + roff[2]);
    short8 hf3 = *(const short8*)(hrow + roff[3]);
    f32x4 a0 = {0.f, 0.f, 0.f, 0.f}, a1 = a0, a2 = a0, a3 = a0;
    a0 = __builtin_amdgcn_mfma_f32_16x16x32_bf16(wf[4],  hf0, a0, 0, 0, 0);
    a1 = __builtin_amdgcn_mfma_f32_16x16x32_bf16(wf[12], hf0, a1, 0, 0, 0);
    a2 = __builtin_amdgcn_mfma_f32_16x16x32_bf16(wf[20], hf0, a2, 0, 0, 0);
    a3 = __builtin_amdgcn_mfma_f32_16x16x32_bf16(wf[28], hf0, a3, 0, 0, 0);
    a0 = __builtin_amdgcn_mfma_f32_16x16x32_bf16(wf[5],  hf1, a0, 0, 0, 0);
    a1 = __builtin_amdgcn_mfma_f32_16x16x32_bf16(wf[13], hf1, a1, 0, 0, 0);
    a2 = __builtin_amdgcn_mfma_f32_16x16x32_bf16(wf[21], hf1, a2, 0, 0, 0);
    a3 = __builtin_amdgcn_mfma_f32_16x16x32_bf16(wf[29], hf1, a3, 0, 0, 0);
    a0 = __builtin_amdgcn_mfma_f32_16x16x32_bf16(wf[6],  hf2, a0, 0, 0, 0);
    a1 = __builtin_amdgcn_mfma_f32_16x16x32_bf16(wf[14], hf2, a1, 0, 0, 0);
    a2 = __builtin_amdgcn_mfma_f32_16x16x32_bf16(wf[22], hf2, a2, 0, 0, 0);
    a3 = __builtin_amdgcn_mfma_f32_16x16x32_bf16(wf[30], hf2, a3, 0, 0, 0);
    a0 = __builtin_amdgcn_mfma_f32_16x16x32_bf16(wf[7],  hf3, a0, 0, 0, 0);
    a1 = __builtin_amdgcn_mfma_f32_16x16x32_bf16(wf[15], hf3, a1, 0, 0, 0);
    a2 = __builtin_amdgcn_mfma_f32_16x16x32_bf16(wf[23], hf3, a2, 0, 0, 0);
    a3 = __builtin_amdgcn_mfma_f32_16x16x32_bf16(wf[31], hf3, a3, 0, 0, 0);
    // ---- select own tile (lane-varying cndmask, no runtime indexing) ----
    f32x4 zA = (so & 2) ? a2 : a0;
    f32x4 zB = (so & 2) ? a3 : a1;
    f32x4 zh = (so & 1) ? zB : zA;
    f32x4 zx = *(const f32x4*)&xstage[(t & 3) * 4 + cbv][w * 64 + so * 16 + g4 * 4];
    float z0 = zh[0] + zx[0];
    float z1 = zh[1] + zx[1];
    float z2 = zh[2] + zx[2];
    float z3 = zh[3] + zx[3];
    float A2 = ex2(-z0);                   // e^-zi
    float B2 = ex2(z1);                    // e^{2zj}
    float F2 = ex2(-z2);                   // e^-(zf+1)
    float O2 = ex2(-z3);                   // e^-zo
    float r1 = rcp_f((1.f + A2) * (1.f + B2));
    float rf = rcp_f(1.f + F2);
    float cn = fmaf(c, rf, (B2 - 1.f) * r1);
    c = cn;
    float C2 = ex2(cn * TL2E);             // e^{2c}
    float r2 = rcp_f((1.f + C2) * (1.f + O2));
    float hv = (C2 - 1.f) * r2;            // tanh(c)*sig(zo)
    u16 hb16 = f2bf(hv);
    hbuf[NXT][cbv][u_so] = hb16;           // all 64 lanes, bijective coverage
    *ph = hb16;
    ph += step1;
    asm volatile("s_waitcnt lgkmcnt(0)" ::: "memory");
    __builtin_amdgcn_s_barrier();
    asm volatile("" ::: "memory");
    if ((t & 3) == 3 && t < 508) {
      // x-block for steps t+1 .. t+4 (B1 above separates all xstage reads from this)
#pragma unroll
      for (int n = 0; n < 4; n++) {
        f32x4 xacc = bias4[n];
        xacc = __builtin_amdgcn_mfma_f32_16x16x32_bf16(wf[n * 8 + 0], xblk[0], xacc, 0, 0, 0);
        xacc = __builtin_amdgcn_mfma_f32_16x16x32_bf16(wf[n * 8 + 1], xblk[1], xacc, 0, 0, 0);
        xacc = __builtin_amdgcn_mfma_f32_16x16x32_bf16(wf[n * 8 + 2], xblk[2], xacc, 0, 0, 0);
        xacc = __builtin_amdgcn_mfma_f32_16x16x32_bf16(wf[n * 8 + 3], xblk[3], xacc, 0, 0, 0);
        *(f32x4*)((char*)&xstage[cb][0] + xcol + n * 64) = xacc;
      }
      int ts = t + 5 + so;                 // next block's step for this lane
      if (ts > 511) ts = 511;              // clamp: in-bounds, value unused
      const u16* p = xb0 + (long)ts * step1;
#pragma unroll
      for (int ks = 0; ks < 4; ks++) xblk[ks] = *(const short8*)(p + ks * 32);
      asm volatile("s_waitcnt lgkmcnt(0)" ::: "memory");
      __builtin_amdgcn_s_barrier();
      asm volatile("" ::: "memory");
    }
  }
}

// ---------------- attention + FC + argmax (+ fused l2 at block 128, r16-proven) ----
__global__ __launch_bounds__(512) void k_attn(const u16* __restrict__ hsf,
                                              const u16* __restrict__ hsb,
                                              const float* __restrict__ att_w,
                                              const float* __restrict__ fc_w,
                                              const float* __restrict__ fc_b,
                                              float* __restrict__ out) {
  __shared__ float rsum[8][128];
  __shared__ float esums[8];
  __shared__ float hstar[128];
  __shared__ float lg[NCLS];
  int tid = threadIdx.x, b = blockIdx.x;
  int w = tid >> 6, l = tid & 63;
  if (b == 128) {                       // fused l2 loss
    float a = 0.f;
    for (int i = tid; i < 128 * NCLS; i += 512) a += fc_w[i] * fc_w[i];
    if (tid < NCLS) a += fc_b[tid] * fc_b[tid];
#pragma unroll
    for (int o2 = 32; o2 >= 1; o2 >>= 1) a += __shfl_xor(a, o2, 64);
    if (l == 0) esums[w] = a;
    __syncthreads();
    if (tid == 0) {
      float s = 0.f;
#pragma unroll
      for (int i = 0; i < 8; i++) s += esums[i];
      out[2560] = 0.5f * s;
    }
    return;
  }
  float2 aw = *(const float2*)(att_w + 2 * l);
  float r0 = 0.f, r1 = 0.f, es = 0.f;
  for (int t = w; t < T_LEN; t += 8) {
    size_t o = ((size_t)t * 128 + b) * 128 + 2 * l;
    u32 vf = *(const u32*)(hsf + o);
    u32 vb = *(const u32*)(hsb + o);
    float h0 = bf2f((u16)vf) + bf2f((u16)vb);
    float h1 = bf2f((u16)(vf >> 16)) + bf2f((u16)(vb >> 16));
    float e0 = ex2(h0 * TL2E);
    float th0 = (e0 - 1.f) * rcp_f(e0 + 1.f);
    float e1 = ex2(h1 * TL2E);
    float th1 = (e1 - 1.f) * rcp_f(e1 + 1.f);
    float s = fmaf(th0, aw.x, th1 * aw.y);
#pragma unroll
    for (int o2 = 32; o2 >= 1; o2 >>= 1) s += __shfl_xor(s, o2, 64);
    float e = ex2(s * L2E);      // no max-subtraction: |s| bounded, e^s safe in f32
    r0 = fmaf(e, h0, r0); r1 = fmaf(e, h1, r1); es += e;
  }
  rsum[w][2 * l] = r0;
  rsum[w][2 * l + 1] = r1;
  if (l == 0) esums[w] = es;
  __syncthreads();
  if (tid < 128) {
    float r = 0.f, et = 0.f;
#pragma unroll
    for (int i = 0; i < 8; i++) { r += rsum[i][tid]; et += esums[i]; }
    float rr = r / et;
    float e2 = ex2(rr * TL2E);
    hstar[tid] = (e2 - 1.f) * rcp_f(e2 + 1.f);
  }
  __syncthreads();
  if (tid < NCLS) {
    float acc = fc_b[tid];
#pragma unroll 4
    for (int hh = 0; hh < 128; hh++) acc = fmaf(hstar[hh], fc_w[hh * NCLS + tid], acc);
    out[b * NCLS + tid] = acc;
    lg[tid] = acc;
  }
  __syncthreads();
  if (tid == 0) {
    int best = 0; float bv = lg[0];
    for (int l2 = 1; l2 < NCLS; l2++)
      if (lg[l2] > bv) { bv = lg[l2]; best = l2; }
    out[2432 + b] = (float)best;   // predict_label_ids
    out[2561 + b] = (float)best;   // probabilities (argmax of softmax == argmax)
  }
}

extern "C" void kernel_launch(void* const* d_in, const int* in_sizes, int n_in,
                              void* d_out, int out_size, void* d_ws, size_t ws_size,
                              hipStream_t stream) {
  const int* ids = (const int*)d_in[0];
  const float* table = (const float*)d_in[1];
  const float* fw_k = (const float*)d_in[2];
  const float* fw_b = (const float*)d_in[3];
  const float* bw_k = (const float*)d_in[4];
  const float* bw_b = (const float*)d_in[5];
  const float* att_w = (const float*)d_in[6];
  const float* fc_w = (const float*)d_in[7];
  const float* fc_b = (const float*)d_in[8];
  float* out = (float*)d_out;
  char* ws = (char*)d_ws;

  u16* xs = (u16*)(ws + 0);                    // 16,777,216 B   xs[t*128+b][128] bf16
  u16* wt_bf = (u16*)(ws + 16777216);          //    524,288 B   [2][512][256] bf16
  float* bias_pre = (float*)(ws + 17301504);   //      4,096 B
  u16* hs_fw = (u16*)(ws + 17305600);          // 16,777,216 B   [t][b][u] bf16
  u16* hs_bw = (u16*)(ws + 34082816);          // 16,777,216 B   (end 50,860,032)

  hipLaunchKernelGGL(k_embed_prep, dim3(9217), dim3(256), 0, stream, ids, table,
                     fw_k, bw_k, fw_b, bw_b, xs, wt_bf, bias_pre);
  hipLaunchKernelGGL(k_lstm, dim3(64), dim3(512), 0, stream, wt_bf, bias_pre, xs,
                     hs_fw, hs_bw);
  hipLaunchKernelGGL(k_attn, dim3(129), dim3(512), 0, stream, hs_fw, hs_bw, att_w,
                     fc_w, fc_b, out);
}